// Round 5
// baseline (83.322 us; speedup 1.0000x reference)
//
#include <hip/hip_runtime.h>
#include <stdint.h>

#define N 384
#define D 1024
#define N2 (N * N)            // 147456
static constexpr size_t N3 = (size_t)N * N2;  // 56623104

// ---- workspace byte offsets (total ~1.2 MB) ----
static constexpr size_t MAT_OFF = 0;              // 147456*8 = 1179648
static constexpr size_t TN_OFF  = 1179648;
static constexpr size_t TC_OFF  = 1182720;
static constexpr size_t ANS_OFF = 1185792;
static constexpr size_t ANC_OFF = 1188864;
static constexpr size_t HP_OFF  = 1191936;        // 384 ints

static constexpr int GEMM_BLOCKS = 144;           // 12x12 tiles, full K
static constexpr int FILL_BLOCKS = 2048;
static constexpr int COND_F4     = 14155776;      // N3/4 float4 quads

// =============== K1: mega — fp64 GEMM (inline norms) + cond fill =========
// blocks [0,144): 32x32 output tile, K=1024. Row norms accumulated during
//   staging (fixed order -> deterministic), applied + negated at epilogue.
//   Writes mat directly.
// blocks [144, 2192): grid-stride float4 zero-fill of cond, SKIPPING rows
//   (a,p) with labs[p]==labs[a] && p!=a (exactly the rows k_sparse writes).
//   an region + tail are skipped entirely (k_sparse writes them fully).
__global__ __launch_bounds__(256) void k_mega(const float* __restrict__ x,
                                              const int* __restrict__ labels,
                                              double* __restrict__ mat,
                                              float4* __restrict__ outv) {
  __shared__ double As[64][32];
  __shared__ double Bs[64][32];
  __shared__ double sqred[2][32][8];
  __shared__ double invnA[32], invnB[32];
  __shared__ int labsF[N];
  int b = blockIdx.x;
  int t = threadIdx.x;

  if (b >= GEMM_BLOCKS) {
    // ---------------- fill path ----------------
    for (int i = t; i < N; i += 256) labsF[i] = labels[i];
    __syncthreads();
    int i = (b - GEMM_BLOCKS) * 256 + t;
    const int stride = FILL_BLOCKS * 256;
    const float4 z = make_float4(0.f, 0.f, 0.f, 0.f);
    for (; i < COND_F4; i += stride) {
      int a = i / 36864;                 // N2/4 quads per anchor
      int rem = i - a * 36864;
      int p = rem / 96;                  // 96 quads per p-row
      if (!(labsF[p] == labsF[a] && p != a)) outv[i] = z;
    }
    return;
  }

  // ---------------- GEMM path ----------------
  int m0 = (b % 12) * 32, n0 = (b / 12) * 32;
  int tm = t & 15, tn = t >> 4;
  double a00 = 0, a01 = 0, a10 = 0, a11 = 0;
  double sqA = 0, sqB = 0;               // this thread's row = t&31 (both h)
  for (int kc = 0; kc < 16; ++kc) {
    int kbase = kc * 64;
#pragma unroll
    for (int h = 0; h < 2; ++h) {
      int f = t + h * 256;               // 0..511
      int m = f & 31, kq = f >> 5;       // kq 0..15
      float4 va = *(const float4*)(x + (size_t)(m0 + m) * D + kbase + kq * 4);
      double ax = va.x, ay = va.y, az = va.z, aw = va.w;
      As[kq * 4 + 0][m] = ax; As[kq * 4 + 1][m] = ay;
      As[kq * 4 + 2][m] = az; As[kq * 4 + 3][m] = aw;
      sqA += ax * ax + ay * ay + az * az + aw * aw;
      float4 vb = *(const float4*)(x + (size_t)(n0 + m) * D + kbase + kq * 4);
      double bx = vb.x, by = vb.y, bz = vb.z, bw = vb.w;
      Bs[kq * 4 + 0][m] = bx; Bs[kq * 4 + 1][m] = by;
      Bs[kq * 4 + 2][m] = bz; Bs[kq * 4 + 3][m] = bw;
      sqB += bx * bx + by * by + bz * bz + bw * bw;
    }
    __syncthreads();
#pragma unroll 8
    for (int k = 0; k < 64; ++k) {
      double ax = As[k][2 * tm], ay = As[k][2 * tm + 1];
      double bx = Bs[k][2 * tn], by = Bs[k][2 * tn + 1];
      a00 = fma(ax, bx, a00);
      a01 = fma(ax, by, a01);
      a10 = fma(ay, bx, a10);
      a11 = fma(ay, by, a11);
    }
    __syncthreads();
  }
  sqred[0][t & 31][t >> 5] = sqA;
  sqred[1][t & 31][t >> 5] = sqB;
  __syncthreads();
  if (t < 64) {
    int which = t >> 5, m = t & 31;
    double s = 0.0;
#pragma unroll
    for (int j = 0; j < 8; ++j) s += sqred[which][m][j];
    double inv = 1.0 / sqrt(s);
    if (which) invnB[m] = inv; else invnA[m] = inv;
  }
  __syncthreads();
  int r0 = m0 + 2 * tm, c0 = n0 + 2 * tn;
  double i0 = invnA[2 * tm], i1 = invnA[2 * tm + 1];
  double j0 = invnB[2 * tn], j1 = invnB[2 * tn + 1];
  mat[(size_t)r0 * N + c0]           = -(a00 * (i0 * j0));
  mat[(size_t)r0 * N + c0 + 1]       = -(a01 * (i0 * j1));
  mat[(size_t)(r0 + 1) * N + c0]     = -(a10 * (i1 * j0));
  mat[(size_t)(r0 + 1) * N + c0 + 1] = -(a11 * (i1 * j1));
}

// =============== K2: per-anchor stats (shfl butterflies) ==================
__global__ __launch_bounds__(384) void k_stats(const double* __restrict__ mat,
                                               const int* __restrict__ labels,
                                               double* __restrict__ tn,
                                               double* __restrict__ tc,
                                               double* __restrict__ ans,
                                               double* __restrict__ anc,
                                               int* __restrict__ hp) {
  __shared__ int labs[N];
  __shared__ int hist[32];
  __shared__ double cw[6][6];
  int a = blockIdx.x, t = threadIdx.x;
  int w = t >> 6, lane = t & 63;
  if (t < 32) hist[t] = 0;
  labs[t] = labels[t];
  __syncthreads();
  atomicAdd(&hist[labs[t] & 31], 1);
  __syncthreads();
  int la = labs[a];
  double m = mat[(size_t)a * N + t];
  bool same = (labs[t] == la) && (t != a);
  bool diff = (labs[t] != la);
  bool hpa = hist[la] >= 2;
  bool hpt = hist[labs[t]] >= 2;
  bool anm = (t > a) && diff && (hpa || hpt);

  double q[6];
  q[0] = same ? m : 0.0;
  q[1] = same ? 1.0 : 0.0;
  q[2] = diff ? m : 0.0;
  q[3] = diff ? 1.0 : 0.0;
  q[4] = anm ? m : 0.0;
  q[5] = anm ? 1.0 : 0.0;
#pragma unroll
  for (int i = 0; i < 6; ++i) {
#pragma unroll
    for (int s = 32; s; s >>= 1) q[i] += __shfl_xor(q[i], s, 64);
  }
  if (lane == 0) {
#pragma unroll
    for (int i = 0; i < 6; ++i) cw[w][i] = q[i];
  }
  __syncthreads();
  if (t == 0) {
    double r[6];
#pragma unroll
    for (int i = 0; i < 6; ++i) {
      double s = 0.0;
      for (int ww = 0; ww < 6; ++ww) s += cw[ww][i];
      r[i] = s;
    }
    tn[a]  = r[2] * r[1] - r[0] * r[3];
    tc[a]  = r[1] * r[3];
    ans[a] = r[4];
    anc[a] = r[5];
    hp[a]  = hpa ? 1 : 0;
  }
}

// =============== K3: sparse — scalars (redundant) + same-rows + an ========
__global__ __launch_bounds__(256) void k_sparse(const double* __restrict__ mat,
                                                const int* __restrict__ labels,
                                                const int* __restrict__ hp,
                                                const double* __restrict__ tn,
                                                const double* __restrict__ tc,
                                                const double* __restrict__ ans,
                                                const double* __restrict__ anc,
                                                float* __restrict__ out) {
  __shared__ int labs[N];
  __shared__ int hpL[N];
  __shared__ double matA[N];
  __shared__ int list[N];
  __shared__ int cnt;
  __shared__ double sEps, sBeta;
  int a = blockIdx.x, t = threadIdx.x;
  for (int i = t; i < N; i += 256) {
    labs[i] = labels[i];
    hpL[i] = hp[i];
    matA[i] = mat[(size_t)a * N + i];
  }
  if (t == 0) cnt = 0;
  // wave 0: global scalar reduce (same order as the passing r4 k_final)
  if (t < 64) {
    double vtn = 0, vtc = 0, vas = 0, vac = 0;
#pragma unroll
    for (int j = 0; j < 6; ++j) {
      int idx = t + 64 * j;
      vtn += tn[idx]; vtc += tc[idx]; vas += ans[idx]; vac += anc[idx];
    }
#pragma unroll
    for (int s = 32; s; s >>= 1) {
      vtn += __shfl_xor(vtn, s, 64);
      vtc += __shfl_xor(vtc, s, 64);
      vas += __shfl_xor(vas, s, 64);
      vac += __shfl_xor(vac, s, 64);
    }
    if (t == 0) {
      double an_mean = vas / fmax(vac, 1.0);
      double beta = 1.0 + ((-an_mean) - 1.0) / 2.0;
      double em = vtn / fmax(vtc, 1.0);
      double eps = em / 2.0;
      eps = eps < 0.0 ? 0.0 : (eps > 0.5 ? 0.5 : eps);
      sEps = eps;
      sBeta = beta;
      if (a == 0) {
        out[N3 + N2]     = (float)eps;
        out[N3 + N2 + 1] = (float)beta;
      }
    }
  }
  __syncthreads();
  int la = labs[a];
  for (int i = t; i < N; i += 256) {
    if (labs[i] == la && i != a) list[atomicAdd(&cnt, 1)] = i;
  }
  __syncthreads();
  double eps = sEps, beta = sBeta;
  int hpa = hpL[a];
  // an row a (fill skips the whole an region)
  if (t < 96) {
    int b0 = t * 4;
    float r[4];
#pragma unroll
    for (int j = 0; j < 4; ++j) {
      int b = b0 + j;
      bool pm = (a < b) && (labs[b] != la) && (hpa || hpL[b]);
      r[j] = (pm && (-matA[b] >= beta)) ? 1.0f : 0.0f;
    }
    *((float4*)(out + N3 + (size_t)a * N + b0)) =
        make_float4(r[0], r[1], r[2], r[3]);
  }
  // same rows of cond[a] (fill skips exactly these), 2 rows / iteration
  int nc = cnt;
  for (int base = 0; base < nc; base += 2) {
    int rr = base + (t / 96);
    if (t < 192 && rr < nc) {
      int p = list[rr];
      double mp = matA[p];
      int n0 = (t % 96) * 4;
      float r[4];
#pragma unroll
      for (int j = 0; j < 4; ++j) {
        int n = n0 + j;
        double d = matA[n] - mp;
        r[j] = ((labs[n] != la) && (d > 0.0) && (d <= eps)) ? 1.0f : 0.0f;
      }
      *((float4*)(out + (size_t)a * N2 + (size_t)p * N + n0)) =
          make_float4(r[0], r[1], r[2], r[3]);
    }
  }
}

extern "C" void kernel_launch(void* const* d_in, const int* in_sizes, int n_in,
                              void* d_out, int out_size, void* d_ws, size_t ws_size,
                              hipStream_t stream) {
  const float* logits = (const float*)d_in[0];
  const int* labels = (const int*)d_in[1];
  float* out = (float*)d_out;
  char* ws = (char*)d_ws;
  double* mat = (double*)(ws + MAT_OFF);
  double* tn  = (double*)(ws + TN_OFF);
  double* tc  = (double*)(ws + TC_OFF);
  double* ans = (double*)(ws + ANS_OFF);
  double* anc = (double*)(ws + ANC_OFF);
  int* hp     = (int*)(ws + HP_OFF);

  k_mega<<<dim3(GEMM_BLOCKS + FILL_BLOCKS), dim3(256), 0, stream>>>(
      logits, labels, mat, (float4*)out);
  k_stats<<<dim3(N), dim3(384), 0, stream>>>(mat, labels, tn, tc, ans, anc, hp);
  k_sparse<<<dim3(N), dim3(256), 0, stream>>>(mat, labels, hp, tn, tc, ans,
                                              anc, out);
}

// Round 6
// 52.471 us; speedup vs baseline: 1.5880x; 1.5880x over previous
//
#include <hip/hip_runtime.h>
#include <stdint.h>

#define N 384
#define D 1024
#define N2 (N * N)            // 147456
static constexpr size_t N3 = (size_t)N * N2;  // 56623104

// ---- workspace byte offsets (total ~7.1 MB) ----
static constexpr size_t PART_OFF = 0;              // 4*147456*8 = 4718592
static constexpr size_t MAT_OFF  = 4718592;        // 147456*8   = 1179648
static constexpr size_t INVN_OFF = 5898240;        // 384*8
static constexpr size_t TN_OFF   = 5901312;
static constexpr size_t TC_OFF   = 5904384;
static constexpr size_t ANS_OFF  = 5907456;
static constexpr size_t ANC_OFF  = 5910528;
static constexpr size_t HP_OFF   = 5913600;        // 384 ints
// scalars folded into k_sparse

static constexpr int GEMM_BLOCKS = 576;            // 12x12 tiles x K-split 4
static constexpr int NORM_BLOCKS = 96;             // 4 rows per block
static constexpr int FILL_BLOCKS = 2048;
static constexpr int FILL_F4     = 14192640;       // (N3+N2)/4 quads

// =============== K1: mega — GEMM partials ∥ invnorm ∥ pure fill ==========
// blocks [0,576): fp64 GEMM 32x32 tile, K=256 (bz = b/144), raw dots.
// blocks [576,672): per-row 1/||x|| (4 rows/block, one wave per row).
// blocks [672,2720): grid-stride float4 zero-fill of cond+an (pure stream).
__global__ __launch_bounds__(256) void k_mega(const float* __restrict__ x,
                                              double* __restrict__ part,
                                              double* __restrict__ invn,
                                              float4* __restrict__ outv) {
  __shared__ double As[64][32];
  __shared__ double Bs[64][32];
  int b = blockIdx.x;
  int t = threadIdx.x;

  if (b >= GEMM_BLOCKS + NORM_BLOCKS) {
    // ---------------- fill path: pure store stream ----------------
    int i = (b - GEMM_BLOCKS - NORM_BLOCKS) * 256 + t;
    const int stride = FILL_BLOCKS * 256;
    const float4 z = make_float4(0.f, 0.f, 0.f, 0.f);
    for (; i < FILL_F4; i += stride) outv[i] = z;
    return;
  }
  if (b >= GEMM_BLOCKS) {
    // ---------------- invnorm path ----------------
    int w = t >> 6, lane = t & 63;
    int a = (b - GEMM_BLOCKS) * 4 + w;
    const float4* row = (const float4*)(x + (size_t)a * D);
    double s = 0.0;
#pragma unroll
    for (int j = 0; j < 4; ++j) {
      float4 v = row[lane + 64 * j];
      double dx = v.x, dy = v.y, dz = v.z, dw = v.w;
      s += dx * dx + dy * dy + dz * dz + dw * dw;
    }
#pragma unroll
    for (int m = 32; m; m >>= 1) s += __shfl_xor(s, m, 64);
    if (lane == 0) invn[a] = 1.0 / sqrt(s);
    return;
  }

  // ---------------- GEMM path (K-split 4) ----------------
  int bz = b / 144, rem = b % 144;
  int m0 = (rem % 12) * 32, n0 = (rem / 12) * 32, k0 = bz * 256;
  int tm = t & 15, tn = t >> 4;
  double a00 = 0, a01 = 0, a10 = 0, a11 = 0;
  for (int kc = 0; kc < 4; ++kc) {
    int kbase = k0 + kc * 64;
#pragma unroll
    for (int h = 0; h < 2; ++h) {
      int f = t + h * 256;               // 0..511
      int m = f & 31, kq = f >> 5;       // kq 0..15
      float4 va = *(const float4*)(x + (size_t)(m0 + m) * D + kbase + kq * 4);
      As[kq * 4 + 0][m] = (double)va.x; As[kq * 4 + 1][m] = (double)va.y;
      As[kq * 4 + 2][m] = (double)va.z; As[kq * 4 + 3][m] = (double)va.w;
      float4 vb = *(const float4*)(x + (size_t)(n0 + m) * D + kbase + kq * 4);
      Bs[kq * 4 + 0][m] = (double)vb.x; Bs[kq * 4 + 1][m] = (double)vb.y;
      Bs[kq * 4 + 2][m] = (double)vb.z; Bs[kq * 4 + 3][m] = (double)vb.w;
    }
    __syncthreads();
#pragma unroll 8
    for (int k = 0; k < 64; ++k) {
      double ax = As[k][2 * tm], ay = As[k][2 * tm + 1];
      double bx = Bs[k][2 * tn], by = Bs[k][2 * tn + 1];
      a00 = fma(ax, bx, a00);
      a01 = fma(ax, by, a01);
      a10 = fma(ay, bx, a10);
      a11 = fma(ay, by, a11);
    }
    __syncthreads();
  }
  double* o = part + (size_t)bz * N2;
  int r0 = m0 + 2 * tm, c0 = n0 + 2 * tn;
  o[(size_t)r0 * N + c0]           = a00;
  o[(size_t)r0 * N + c0 + 1]       = a01;
  o[(size_t)(r0 + 1) * N + c0]     = a10;
  o[(size_t)(r0 + 1) * N + c0 + 1] = a11;
}

// =============== K2: partial-sum + norm-scale + per-anchor stats ==========
__global__ __launch_bounds__(384) void k_stats(const double* __restrict__ part,
                                               const double* __restrict__ invn,
                                               const int* __restrict__ labels,
                                               double* __restrict__ mat,
                                               double* __restrict__ tn,
                                               double* __restrict__ tc,
                                               double* __restrict__ ans,
                                               double* __restrict__ anc,
                                               int* __restrict__ hp) {
  __shared__ int labs[N];
  __shared__ int hist[32];
  __shared__ double cw[6][6];
  int a = blockIdx.x, t = threadIdx.x;
  int w = t >> 6, lane = t & 63;
  if (t < 32) hist[t] = 0;
  labs[t] = labels[t];
  __syncthreads();
  atomicAdd(&hist[labs[t] & 31], 1);
  __syncthreads();
  int la = labs[a];
  size_t idx = (size_t)a * N + t;
  double s = part[idx];
  s += part[(size_t)N2 + idx];
  s += part[2 * (size_t)N2 + idx];
  s += part[3 * (size_t)N2 + idx];
  double m = -(s * (invn[a] * invn[t]));
  mat[idx] = m;
  bool same = (labs[t] == la) && (t != a);
  bool diff = (labs[t] != la);
  bool hpa = hist[la] >= 2;
  bool hpt = hist[labs[t]] >= 2;
  bool anm = (t > a) && diff && (hpa || hpt);

  double q[6];
  q[0] = same ? m : 0.0;
  q[1] = same ? 1.0 : 0.0;
  q[2] = diff ? m : 0.0;
  q[3] = diff ? 1.0 : 0.0;
  q[4] = anm ? m : 0.0;
  q[5] = anm ? 1.0 : 0.0;
#pragma unroll
  for (int i = 0; i < 6; ++i) {
#pragma unroll
    for (int s2 = 32; s2; s2 >>= 1) q[i] += __shfl_xor(q[i], s2, 64);
  }
  if (lane == 0) {
#pragma unroll
    for (int i = 0; i < 6; ++i) cw[w][i] = q[i];
  }
  __syncthreads();
  if (t == 0) {
    double r[6];
#pragma unroll
    for (int i = 0; i < 6; ++i) {
      double s3 = 0.0;
      for (int ww = 0; ww < 6; ++ww) s3 += cw[ww][i];
      r[i] = s3;
    }
    tn[a]  = r[2] * r[1] - r[0] * r[3];
    tc[a]  = r[1] * r[3];
    ans[a] = r[4];
    anc[a] = r[5];
    hp[a]  = hpa ? 1 : 0;
  }
}

// =============== K3: sparse — scalars (redundant) + same-rows + an ========
__global__ __launch_bounds__(256) void k_sparse(const double* __restrict__ mat,
                                                const int* __restrict__ labels,
                                                const int* __restrict__ hp,
                                                const double* __restrict__ tn,
                                                const double* __restrict__ tc,
                                                const double* __restrict__ ans,
                                                const double* __restrict__ anc,
                                                float* __restrict__ out) {
  __shared__ int labs[N];
  __shared__ int hpL[N];
  __shared__ double matA[N];
  __shared__ int list[N];
  __shared__ int cnt;
  __shared__ double sEps, sBeta;
  int a = blockIdx.x, t = threadIdx.x;
  for (int i = t; i < N; i += 256) {
    labs[i] = labels[i];
    hpL[i] = hp[i];
    matA[i] = mat[(size_t)a * N + i];
  }
  if (t == 0) cnt = 0;
  // wave 0: global scalar reduce (deterministic fixed order)
  if (t < 64) {
    double vtn = 0, vtc = 0, vas = 0, vac = 0;
#pragma unroll
    for (int j = 0; j < 6; ++j) {
      int idx = t + 64 * j;
      vtn += tn[idx]; vtc += tc[idx]; vas += ans[idx]; vac += anc[idx];
    }
#pragma unroll
    for (int s = 32; s; s >>= 1) {
      vtn += __shfl_xor(vtn, s, 64);
      vtc += __shfl_xor(vtc, s, 64);
      vas += __shfl_xor(vas, s, 64);
      vac += __shfl_xor(vac, s, 64);
    }
    if (t == 0) {
      double an_mean = vas / fmax(vac, 1.0);
      double beta = 1.0 + ((-an_mean) - 1.0) / 2.0;
      double em = vtn / fmax(vtc, 1.0);
      double eps = em / 2.0;
      eps = eps < 0.0 ? 0.0 : (eps > 0.5 ? 0.5 : eps);
      sEps = eps;
      sBeta = beta;
      if (a == 0) {
        out[N3 + N2]     = (float)eps;
        out[N3 + N2 + 1] = (float)beta;
      }
    }
  }
  __syncthreads();
  int la = labs[a];
  for (int i = t; i < N; i += 256) {
    if (labs[i] == la && i != a) list[atomicAdd(&cnt, 1)] = i;
  }
  __syncthreads();
  double eps = sEps, beta = sBeta;
  int hpa = hpL[a];
  // an row a
  if (t < 96) {
    int b0 = t * 4;
    float r[4];
#pragma unroll
    for (int j = 0; j < 4; ++j) {
      int b = b0 + j;
      bool pm = (a < b) && (labs[b] != la) && (hpa || hpL[b]);
      r[j] = (pm && (-matA[b] >= beta)) ? 1.0f : 0.0f;
    }
    *((float4*)(out + N3 + (size_t)a * N + b0)) =
        make_float4(r[0], r[1], r[2], r[3]);
  }
  // same rows of cond[a], 2 rows per iteration (threads 0..191)
  int nc = cnt;
  for (int base = 0; base < nc; base += 2) {
    int rr = base + (t / 96);
    if (t < 192 && rr < nc) {
      int p = list[rr];
      double mp = matA[p];
      int n0 = (t % 96) * 4;
      float r[4];
#pragma unroll
      for (int j = 0; j < 4; ++j) {
        int n = n0 + j;
        double d = matA[n] - mp;
        r[j] = ((labs[n] != la) && (d > 0.0) && (d <= eps)) ? 1.0f : 0.0f;
      }
      *((float4*)(out + (size_t)a * N2 + (size_t)p * N + n0)) =
          make_float4(r[0], r[1], r[2], r[3]);
    }
  }
}

extern "C" void kernel_launch(void* const* d_in, const int* in_sizes, int n_in,
                              void* d_out, int out_size, void* d_ws, size_t ws_size,
                              hipStream_t stream) {
  const float* logits = (const float*)d_in[0];
  const int* labels = (const int*)d_in[1];
  float* out = (float*)d_out;
  char* ws = (char*)d_ws;
  double* part = (double*)(ws + PART_OFF);
  double* mat  = (double*)(ws + MAT_OFF);
  double* invn = (double*)(ws + INVN_OFF);
  double* tn   = (double*)(ws + TN_OFF);
  double* tc   = (double*)(ws + TC_OFF);
  double* ans  = (double*)(ws + ANS_OFF);
  double* anc  = (double*)(ws + ANC_OFF);
  int* hp      = (int*)(ws + HP_OFF);

  k_mega<<<dim3(GEMM_BLOCKS + NORM_BLOCKS + FILL_BLOCKS), dim3(256), 0,
           stream>>>(logits, part, invn, (float4*)out);
  k_stats<<<dim3(N), dim3(384), 0, stream>>>(part, invn, labels, mat, tn, tc,
                                             ans, anc, hp);
  k_sparse<<<dim3(N), dim3(256), 0, stream>>>(mat, labels, hp, tn, tc, ans,
                                              anc, out);
}